// Round 1
// baseline (252.933 us; speedup 1.0000x reference)
//
#include <hip/hip_runtime.h>
#include <stdint.h>

typedef unsigned short u16;
typedef __bf16 bf16;
typedef bf16 bf16x8 __attribute__((ext_vector_type(8)));
typedef float f32x4 __attribute__((ext_vector_type(4)));
typedef u16 u16x8 __attribute__((ext_vector_type(8)));
typedef u16 u16x4 __attribute__((ext_vector_type(4)));

#define T_SEQ 2048
#define NHEAD 16
#define HD    64
#define CEMB  1024
#define QS    8388608   // elems per q/k/v tensor: 4*16*2048*64
#define QSCALE 0.18033688011112042f   // 0.125 * log2(e); softmax in exp2 domain

__device__ __forceinline__ u16 f2b(float f){
  bf16 h = (bf16)f;
  return __builtin_bit_cast(u16, h);
}
__device__ __forceinline__ void glds16(const void* g, const void* l){
  __builtin_amdgcn_global_load_lds(
    (__attribute__((address_space(1))) unsigned int*)(uintptr_t)g,
    (__attribute__((address_space(3))) unsigned int*)(uintptr_t)l,
    16, 0, 0);
}

// -------- fused prep: x fp32->bf16 (4096 blocks), W_attn T (768), W_proj T (256)
__global__ __launch_bounds__(256) void prep_kernel(
    const float* __restrict__ x, u16* __restrict__ xb,
    const float* __restrict__ Wa, u16* __restrict__ Wta,
    const float* __restrict__ Wp, u16* __restrict__ Wtp)
{
  __shared__ __align__(16) u16 tile[64][72];
  const int bid = blockIdx.x;
  const int tid = threadIdx.x;
  if (bid < 4096){
    const int i = (bid * 256 + tid) * 8;
    f32x4 a = *(const f32x4*)&x[i];
    f32x4 b = *(const f32x4*)&x[i + 4];
    u16x8 h;
    #pragma unroll
    for (int j = 0; j < 4; j++){ h[j] = f2b(a[j]); h[4+j] = f2b(b[j]); }
    *(u16x8*)&xb[i] = h;
    return;
  }
  const float* src; u16* dst; int K, N, bx, by;
  if (bid < 4864){ const int j = bid - 4096; src = Wa; dst = Wta; K = 1024; N = 3072; bx = j % 48; by = j / 48; }
  else           { const int j = bid - 4864; src = Wp; dst = Wtp; K = 1024; N = 1024; bx = j % 16; by = j / 16; }
  const int n0 = bx * 64, k0 = by * 64;
  #pragma unroll
  for (int it = 0; it < 4; it++){
    const int idx = it * 256 + tid;
    const int row = idx >> 4, c4 = (idx & 15) * 4;
    f32x4 v = *(const f32x4*)&src[(size_t)(k0 + row) * N + n0 + c4];
    #pragma unroll
    for (int j = 0; j < 4; j++) tile[row][c4 + j] = f2b(v[j]);
  }
  __syncthreads();
  const int r = tid >> 3, cc = (tid & 7) * 8;
  #pragma unroll
  for (int i = 0; i < 2; i++){
    const int rr = r + i * 32;
    u16x8 v;
    #pragma unroll
    for (int j = 0; j < 8; j++) v[j] = tile[cc + j][rr];
    *(u16x8*)&dst[(size_t)(n0 + rr) * K + k0 + cc] = v;
  }
}

// ================= QKV GEMM: 256x256 tile, BK=64, 8 waves (2Mx4N) =============
// 8-phase-class schedule (4 phases per K-tile, 2 K-tiles in LDS dbuf):
//   strided quadrants so each half-region's LDS reads finish early in the
//   group, allowing in-group prefetch of tile c+2 into the live slot.
// Counted vmcnt(4) once per K-tile (never drained to 0 in steady state).
// st_16x32 LDS swizzle: byte ^= ((byte>>9)&1)<<5, applied on the global
// SOURCE for global_load_lds (linear dest) and on the ds_read address.

#define BARRIER() asm volatile("s_barrier" ::: "memory")
#define WAITV(N)  asm volatile("s_waitcnt vmcnt(" #N ")" ::: "memory")
#define WAITL0()  asm volatile("s_waitcnt lgkmcnt(0)" ::: "memory")

#define STAGE_A(KT, H) do{ \
  const size_t _g = (size_t)(H)*128*(size_t)Ktot + (size_t)(KT)*64; \
  char* _dst = ldsb + ((((KT)&1)*2+(H))<<14) + woff; \
  glds16(asrc0 + _g, _dst); \
  glds16(asrc1 + _g, _dst + 8192); \
}while(0)

#define STAGE_B(KT, H) do{ \
  const size_t _g = (size_t)(H)*128*(size_t)Ktot + (size_t)(KT)*64; \
  char* _dst = ldsb + 65536 + ((((KT)&1)*2+(H))<<14) + woff; \
  glds16(bsrc0 + _g, _dst); \
  glds16(bsrc1 + _g, _dst + 8192); \
}while(0)

#define LDA(D, QM) do{ \
  const char* _b = ldsb + (((D)*2+(QM))<<14) + arf; \
  _Pragma("unroll") \
  for (int mt = 0; mt < 4; mt++){ \
    af[mt][0] = *(const bf16x8*)(_b + mt*2048 + k0off); \
    af[mt][1] = *(const bf16x8*)(_b + mt*2048 + k1off); \
  } \
}while(0)

#define LDB(DST, D, QN) do{ \
  const char* _b = ldsb + 65536 + (((D)*2+(QN))<<14) + brf; \
  _Pragma("unroll") \
  for (int nt = 0; nt < 2; nt++){ \
    DST[nt][0] = *(const bf16x8*)(_b + nt*2048 + k0off); \
    DST[nt][1] = *(const bf16x8*)(_b + nt*2048 + k1off); \
  } \
}while(0)

#define MFMA_QUAD(QM, QN, BF) do{ \
  __builtin_amdgcn_s_setprio(1); \
  _Pragma("unroll") \
  for (int ks = 0; ks < 2; ks++){ \
    _Pragma("unroll") \
    for (int mt = 0; mt < 4; mt++){ \
      _Pragma("unroll") \
      for (int nt = 0; nt < 2; nt++){ \
        acc[QM][mt][QN][nt] = __builtin_amdgcn_mfma_f32_16x16x32_bf16( \
            af[mt][ks], BF[nt][ks], acc[QM][mt][QN][nt], 0, 0, 0); \
      } \
    } \
  } \
  __builtin_amdgcn_s_setprio(0); \
}while(0)

__global__ __launch_bounds__(512, 2) void gemm_qkv(
    const u16* __restrict__ A, const u16* __restrict__ Bt,
    const float* __restrict__ bias, u16* __restrict__ out, int Ktot)
{
  __shared__ __align__(16) char lds_s[131072];   // A: 4x16KB halves, B: same
  char* ldsb = lds_s;
  const int tid = threadIdx.x;
  const int lane = tid & 63, wave = tid >> 6;
  const int l15 = lane & 15, l4 = lane >> 4;
  const int wm = wave >> 2, wn = wave & 3;       // 2 M-waves x 4 N-waves
  const int m0 = blockIdx.y * 256, n0 = blockIdx.x * 256;
  const int NT = Ktot >> 6;                      // assumes NT >= 3
  const int woff = wave * 1024;

  // staging source precompute: phys chunk P -> logical L (involutive XOR)
  int grow0, gcol0, grow1, gcol1;
  { const int P = tid*16;        const int L = P ^ (((P>>9)&1)<<5); grow0 = L>>7; gcol0 = (L&127)>>1; }
  { const int P = 8192 + tid*16; const int L = P ^ (((P>>9)&1)<<5); grow1 = L>>7; gcol1 = (L&127)>>1; }
  const u16* asrc0 = A  + (size_t)(m0 + grow0)*Ktot + gcol0;
  const u16* asrc1 = A  + (size_t)(m0 + grow1)*Ktot + gcol1;
  const u16* bsrc0 = Bt + (size_t)(n0 + grow0)*Ktot + gcol0;
  const u16* bsrc1 = Bt + (size_t)(n0 + grow1)*Ktot + gcol1;

  // ds_read frag addressing: L = rf*128 + ks*64 + l4*16; bit9(L) = rf bit2 = l15 bit2
  const int sw = ((l15 >> 2) & 1) << 5;
  const int k0off = (l4*16) ^ sw;
  const int k1off = (64 + l4*16) ^ sw;
  const int arf = (wm*64 + l15) * 128;           // + mt*2048 per M-frag
  const int brf = (wn*32 + l15) * 128;           // + nt*2048 per N-frag

  f32x4 acc[2][4][2][2] = {};                    // [qm][mt][qn][nt]

  // prologue: tile0 (A0,B0,A1,B1) + tile1 (A0,B0) = 12 loads; keep last 4 in flight
  STAGE_A(0,0); STAGE_B(0,0); STAGE_A(0,1); STAGE_B(0,1);
  STAGE_A(1,0); STAGE_B(1,0);
  WAITV(4);
  BARRIER();

  for (int c = 0; c < NT; c++){
    const int d = c & 1;
    bf16x8 af[4][2], b0[2][2], b1[2][2];

    // phase 0: quad(0,0) -- reads A-half0,B-half0; stage A-half1(c+1)
    LDA(d, 0);
    LDB(b0, d, 0);
    if (c+1 < NT) STAGE_A(c+1, 1);
    BARRIER();
    WAITL0();
    MFMA_QUAD(0, 0, b0);
    BARRIER();

    // phase 1: quad(0,1) -- reads B-half1; stage B-half1(c+1)
    LDB(b1, d, 1);
    if (c+1 < NT) STAGE_B(c+1, 1);
    BARRIER();
    WAITL0();
    MFMA_QUAD(0, 1, b1);
    BARRIER();

    // phase 2: quad(1,0) -- reads A-half1; stage A-half0(c+2) (A-half0 reads done @p1 barrier)
    LDA(d, 1);
    if (c+2 < NT) STAGE_A(c+2, 0);
    BARRIER();
    WAITL0();
    MFMA_QUAD(1, 0, b0);
    BARRIER();

    // phase 3: quad(1,1) -- register-only; stage B-half0(c+2)
    if (c+2 < NT) STAGE_B(c+2, 0);
    BARRIER();
    MFMA_QUAD(1, 1, b1);
    // once-per-K-tile counted wait: tile c+1 fully landed, 4 newest loads may fly
    if (c == NT-2)      WAITV(0);
    else if (c < NT-2)  WAITV(4);
    BARRIER();
  }

  // ---------------- epilogue: qkv scatter (same mapping as before) ------------
  const int which = n0 >> 10;                    // uniform per block: 0=q,1=k,2=v
  #pragma unroll
  for (int qn = 0; qn < 2; qn++){
    #pragma unroll
    for (int nt = 0; nt < 2; nt++){
      const int n = n0 + qn*128 + wn*32 + nt*16 + l15;
      const float bias_v = bias[n];
      const int cc = n & 1023;
      const int h = cc >> 6, dd = cc & 63;
      if (which == 2){
        #pragma unroll
        for (int qm = 0; qm < 2; qm++){
          #pragma unroll
          for (int mt = 0; mt < 4; mt++){
            const int rowg = m0 + qm*128 + wm*64 + mt*16 + l4*4;
            const int bb = rowg >> 11, t = rowg & 2047;
            u16x4 pk;
            #pragma unroll
            for (int r = 0; r < 4; r++) pk[r] = f2b(acc[qm][mt][qn][nt][r] + bias_v);
            *(u16x4*)&out[(size_t)2*QS + ((size_t)(bb*NHEAD + h)*HD + dd)*T_SEQ + t] = pk;
          }
        }
      } else {
        const float sc = (which == 0) ? QSCALE : 1.0f;
        #pragma unroll
        for (int qm = 0; qm < 2; qm++){
          #pragma unroll
          for (int mt = 0; mt < 4; mt++){
            #pragma unroll
            for (int r = 0; r < 4; r++){
              const int rowg = m0 + qm*128 + wm*64 + mt*16 + l4*4 + r;
              const int bb = rowg >> 11, t = rowg & 2047;
              out[(size_t)which*QS + ((size_t)(bb*NHEAD + h)*T_SEQ + t)*HD + dd]
                  = f2b((acc[qm][mt][qn][nt][r] + bias_v) * sc);
            }
          }
        }
      }
    }
  }
}

// ---------------- GEMM (proj): A[M,K](bf16) * Bt[N,K]^T (+bias fp32) ---------
// MODE 1: fp32 [M,N] row-major (d_out). 128x128 tile, 4 waves.
template<int MODE>
__global__ __launch_bounds__(256) void gemm_bt(
    const u16* __restrict__ A, const u16* __restrict__ Bt,
    const float* __restrict__ bias, void* __restrict__ outraw, int Ktot)
{
  __shared__ __align__(16) u16 As[128*64];
  __shared__ __align__(16) u16 Bs[128*64];
  const int tid = threadIdx.x;
  const int lane = tid & 63, wave = tid >> 6;
  const int l15 = lane & 15, l4 = lane >> 4;
  const int wm = wave >> 1, wn = wave & 1;
  const int m0 = blockIdx.y * 128, n0 = blockIdx.x * 128;

  f32x4 acc[4][4] = {};

  for (int k0 = 0; k0 < Ktot; k0 += 64){
    #pragma unroll
    for (int ii = 0; ii < 4; ii++){
      const int slot0 = (wave*4 + ii) * 64;
      const int s = slot0 + lane;
      const int row = s >> 3;
      const int c = (s & 7) ^ (row & 7);
      glds16(&A [(size_t)(m0 + row) * Ktot + k0 + c*8], &As[slot0*8]);
      glds16(&Bt[(size_t)(n0 + row) * Ktot + k0 + c*8], &Bs[slot0*8]);
    }
    __syncthreads();
    #pragma unroll
    for (int ks = 0; ks < 2; ks++){
      bf16x8 af[4], bfr[4];
      #pragma unroll
      for (int mt = 0; mt < 4; mt++){
        const int rf = wm*64 + mt*16 + l15;
        const int slot = rf*8 + ((ks*4 + l4) ^ (rf & 7));
        af[mt] = *(const bf16x8*)&As[slot*8];
      }
      #pragma unroll
      for (int nt = 0; nt < 4; nt++){
        const int rf = wn*64 + nt*16 + l15;
        const int slot = rf*8 + ((ks*4 + l4) ^ (rf & 7));
        bfr[nt] = *(const bf16x8*)&Bs[slot*8];
      }
      #pragma unroll
      for (int mt = 0; mt < 4; mt++)
        #pragma unroll
        for (int nt = 0; nt < 4; nt++)
          acc[mt][nt] = __builtin_amdgcn_mfma_f32_16x16x32_bf16(
              af[mt], bfr[nt], acc[mt][nt], 0, 0, 0);
    }
    __syncthreads();
  }

  #pragma unroll
  for (int nt = 0; nt < 4; nt++){
    const int n = n0 + wn*64 + nt*16 + l15;
    const float bias_v = bias[n];
    if (MODE == 0){
      u16* out = (u16*)outraw;
      const int which = n >> 10;
      const int cc = n & 1023;
      const int h = cc >> 6, d = cc & 63;
      const float sc = (which == 0) ? QSCALE : 1.0f;
      if (which == 2){
        #pragma unroll
        for (int mt = 0; mt < 4; mt++){
          const int rowg = m0 + wm*64 + mt*16 + l4*4;
          const int bb = rowg >> 11, t = rowg & 2047;
          u16x4 pk;
          #pragma unroll
          for (int r = 0; r < 4; r++) pk[r] = f2b(acc[mt][nt][r] + bias_v);
          *(u16x4*)&out[(size_t)2*QS + ((size_t)(bb*NHEAD + h)*HD + d)*T_SEQ + t] = pk;
        }
      } else {
        #pragma unroll
        for (int mt = 0; mt < 4; mt++)
          #pragma unroll
          for (int r = 0; r < 4; r++){
            const int rowg = m0 + wm*64 + mt*16 + l4*4 + r;
            const int bb = rowg >> 11, t = rowg & 2047;
            out[(size_t)which*QS + ((size_t)(bb*NHEAD + t)*0 + (bb*NHEAD + h)*T_SEQ + t)*HD + d]
                = f2b((acc[mt][nt][r] + bias_v) * sc);
          }
      }
    } else {
      float* out = (float*)outraw;
      #pragma unroll
      for (int mt = 0; mt < 4; mt++)
        #pragma unroll
        for (int r = 0; r < 4; r++){
          const int rowg = m0 + wm*64 + mt*16 + l4*4 + r;
          out[(size_t)rowg*CEMB + n] = acc[mt][nt][r] + bias_v;
        }
    }
  }
}

// ---------------- causal flash attention, S^T, no-max softmax ----------------
__global__ __launch_bounds__(256, 4) void attn_kernel(
    const u16* __restrict__ qb, const u16* __restrict__ kb,
    const u16* __restrict__ vtb, u16* __restrict__ y)
{
  __shared__ __align__(16) u16 Ks[64*64];     // swizzled
  __shared__ __align__(16) u16 Vt[64*64];     // swizzled (V^T rows [d][t])
  __shared__ __align__(16) u16 Pw[8*16*72];   // per (wave,group) P[q][t]
  const int tid = threadIdx.x;
  const int lane = tid & 63, wave = tid >> 6;
  const int l15 = lane & 15, l4 = lane >> 4;
  const int qt = 15 - (blockIdx.x >> 6);      // longest-first
  const int bh = blockIdx.x & 63;
  const int q0 = qt * 128;
  const size_t base = (size_t)bh * (T_SEQ * HD);
  const u16* qp  = qb  + base;
  const u16* kp  = kb  + base;
  const u16* vtp = vtb + base;                // [hd][T]

  const int qmin0 = q0 + wave*32;
  const int qmin1 = qmin0 + 16;

  // Q as B-operand frags for both groups
  bf16x8 qf[2][2];
  #pragma unroll
  for (int g = 0; g < 2; g++){
    const int m = qmin0 + g*16 + l15;
    qf[g][0] = *(const bf16x8*)&qp[m*HD +      l4*8];
    qf[g][1] = *(const bf16x8*)&qp[m*HD + 32 + l4*8];
  }
  f32x4 o[2][4] = {};
  float l_run[2] = {0.f, 0.f};

  const int s0i = (wave*2 + 0) * 64 + lane;
  const int s1i = (wave*2 + 1) * 64 + lane;
  const int row0 = s0i >> 3, c0 = (s0i & 7) ^ (row0 & 7);
  const int row1 = s1i >> 3, c1 = (s1i & 7) ^ (row1 & 7);
  const int koff0 = row0*HD + c0*8, koff1 = row1*HD + c1*8;
  const int voff0 = row0*T_SEQ + c0*8, voff1 = row1*T_SEQ + c1*8;
  const int ldso0 = (wave*2 + 0) * 64 * 8, ldso1 = (wave*2 + 1) * 64 * 8;

  const int nkt = 2*qt + 2;
  for (int kt = 0; kt < nkt; kt++){
    __syncthreads();                          // prior tile's LDS reads done
    glds16(&kp [kt*4096 + koff0], &Ks[ldso0]);
    glds16(&kp [kt*4096 + koff1], &Ks[ldso1]);
    glds16(&vtp[kt*64   + voff0], &Vt[ldso0]);
    glds16(&vtp[kt*64   + voff1], &Vt[ldso1]);
    __syncthreads();                          // staged (barrier drains vmcnt)

    const int t0 = kt*64;
    if (t0 <= qmin1 + 15){                    // wave-uniform
      const bool act0 = (t0 <= qmin0 + 15);

      // S^T = K·Q^T for both groups, sharing each K fragment read
      f32x4 s0[4], s1[4];
      #pragma unroll
      for (int nb = 0; nb < 4; nb++){
        f32x4 a0 = {}, a1 = {};
        #pragma unroll
        for (int ks = 0; ks < 2; ks++){
          const int rf = nb*16 + l15;
          const int slot = rf*8 + ((ks*4 + l4) ^ (rf & 7));
          bf16x8 kf = *(const bf16x8*)&Ks[slot*8];
          a1 = __builtin_amdgcn_mfma_f32_16x16x32_bf16(kf, qf[1][ks], a1, 0, 0, 0);
          if (act0)
            a0 = __builtin_amdgcn_mfma_f32_16x16x32_bf16(kf, qf[0][ks], a0, 0, 0, 0);
        }
        s1[nb] = a1; s0[nb] = a0;
      }

      // softmax (exp2 domain, no max tracking) + P write, per group
      #pragma unroll
      for (int g = 0; g < 2; g++){
        if (g == 0 && !act0) continue;
        f32x4* sf = (g == 0) ? s0 : s1;
        const int qmin = (g == 0) ? qmin0 : qmin1;
        const int qg = qmin + l15;
        float lsum = 0.f;
        if (t0 + 63 > qmin){                  // diagonal-region tile: mask
          #pragma unroll
          for (int nb = 0; nb < 4; nb++){
            u16x4 pk;
            #pragma unroll
            for (int r = 0; r < 4; r++){
              const int t = t0 + nb*16 + l4*4 + r;
              float p = __builtin_amdgcn_exp2f(sf[nb][r]);
              p = (t <= qg) ? p : 0.0f;
              lsum += p;
              pk[r] = f2b(p);
            }
            *(u16x4*)&Pw[(wave*2 + g)*1152 + l15*72 + nb*16 + l4*4] = pk;
          }
        } else {
          #pragma unroll
          for (int nb = 0; nb < 4; nb++){
            u16x4 pk;
            #pragma unroll
            for (int r = 0; r < 4; r++){
              const float p = __builtin_amdgcn_exp2f(sf[nb][r]);
              lsum += p;
              pk[r] = f2b(p);
            }
            *(u16x4*)&Pw[(wave*2 + g)*1152 + l15*72 + nb*16 + l4*4] = pk;
          }
        }
        l_run[g] += lsum;
      }

      // O^T += V^T·P^T, sharing each V fragment read between groups
      #pragma unroll
      for (int ks = 0; ks < 2; ks++){
        bf16x8 pf1 = *(const bf16x8*)&Pw[(wave*2 + 1)*1152 + l15*72 + ks*32 + l4*8];
        bf16x8 pf0;
        if (act0) pf0 = *(const bf16x8*)&Pw[(wave*2 + 0)*1152 + l15*72 + ks*32 + l4*8];
        #pragma unroll
        for (int nh = 0; nh < 4; nh++){
          const int rf = nh*16 + l15;
          const int slot = rf*8 + ((ks*4 + l4) ^ (rf & 7));
          bf16x8 vf = *(const bf16x8*)&Vt[slot*8];
          o[1][nh] = __builtin_amdgcn_mfma_f32_16x16x32_bf16(vf, pf1, o[1][nh], 0, 0, 0);
          if (act0)
            o[0][nh] = __builtin_amdgcn_mfma_f32_16x16x32_bf16(vf, pf0, o[0][nh], 0, 0, 0);
        }
      }
    }
  }

  // epilogue per group: O^T[d][q]; lane q = l15; d = nh*16 + l4*4 + r
  const int b = bh >> 4, h = bh & 15;
  #pragma unroll
  for (int g = 0; g < 2; g++){
    float lr = l_run[g];
    lr += __shfl_xor(lr, 16);
    lr += __shfl_xor(lr, 32);
    const float inv_l = 1.0f / lr;
    const int t = qmin0 + g*16 + l15;
    #pragma unroll
    for (int nh = 0; nh < 4; nh++){
      u16x4 pk;
      #pragma unroll
      for (int r = 0; r < 4; r++) pk[r] = f2b(o[g][nh][r] * inv_l);
      *(u16x4*)&y[((size_t)(b*T_SEQ + t))*CEMB + h*HD + nh*16 + l4*4] = pk;
    }
  }
}

extern "C" void kernel_launch(void* const* d_in, const int* in_sizes, int n_in,
                              void* d_out, int out_size, void* d_ws, size_t ws_size,
                              hipStream_t stream) {
  const float* x      = (const float*)d_in[0];
  const float* W_attn = (const float*)d_in[1];
  const float* b_attn = (const float*)d_in[2];
  const float* W_proj = (const float*)d_in[3];
  const float* b_proj = (const float*)d_in[4];
  float* out = (float*)d_out;
  u16* ws  = (u16*)d_ws;

  u16* Wt_attn = ws;                 // 3,145,728
  u16* Wt_proj = ws + 3145728;       // 1,048,576
  u16* xb      = ws + 4194304;       // 8,388,608 (x as bf16; reused as y)
  u16* qkv     = ws + 12582912;      // 3 * QS
  u16* y       = xb;                 // xb dead after QKV GEMM

  prep_kernel<<<5120, 256, 0, stream>>>(x, xb, W_attn, Wt_attn, W_proj, Wt_proj);
  gemm_qkv<<<dim3(12, 32), 512, 0, stream>>>(xb, Wt_attn, b_attn, qkv, 1024);
  attn_kernel<<<1024, 256, 0, stream>>>(qkv, qkv + QS, qkv + 2*QS, y);
  gemm_bt<1><<<dim3(8, 64), 256, 0, stream>>>(y, Wt_proj, b_proj, out, 1024);
}

// Round 2
// 246.177 us; speedup vs baseline: 1.0274x; 1.0274x over previous
//
#include <hip/hip_runtime.h>
#include <stdint.h>

typedef unsigned short u16;
typedef __bf16 bf16;
typedef bf16 bf16x8 __attribute__((ext_vector_type(8)));
typedef float f32x4 __attribute__((ext_vector_type(4)));
typedef u16 u16x8 __attribute__((ext_vector_type(8)));
typedef u16 u16x4 __attribute__((ext_vector_type(4)));

#define T_SEQ 2048
#define NHEAD 16
#define HD    64
#define CEMB  1024
#define QS    8388608   // elems per q/k/v tensor: 4*16*2048*64
#define QSCALE 0.18033688011112042f   // 0.125 * log2(e); softmax in exp2 domain

__device__ __forceinline__ u16 f2b(float f){
  bf16 h = (bf16)f;
  return __builtin_bit_cast(u16, h);
}
__device__ __forceinline__ void glds16(const void* g, const void* l){
  __builtin_amdgcn_global_load_lds(
    (__attribute__((address_space(1))) unsigned int*)(uintptr_t)g,
    (__attribute__((address_space(3))) unsigned int*)(uintptr_t)l,
    16, 0, 0);
}

// -------- fused prep: x fp32->bf16 (4096 blocks), W_attn T (768), W_proj T (256)
__global__ __launch_bounds__(256) void prep_kernel(
    const float* __restrict__ x, u16* __restrict__ xb,
    const float* __restrict__ Wa, u16* __restrict__ Wta,
    const float* __restrict__ Wp, u16* __restrict__ Wtp)
{
  __shared__ __align__(16) u16 tile[64][72];
  const int bid = blockIdx.x;
  const int tid = threadIdx.x;
  if (bid < 4096){
    const int i = (bid * 256 + tid) * 8;
    f32x4 a = *(const f32x4*)&x[i];
    f32x4 b = *(const f32x4*)&x[i + 4];
    u16x8 h;
    #pragma unroll
    for (int j = 0; j < 4; j++){ h[j] = f2b(a[j]); h[4+j] = f2b(b[j]); }
    *(u16x8*)&xb[i] = h;
    return;
  }
  const float* src; u16* dst; int K, N, bx, by;
  if (bid < 4864){ const int j = bid - 4096; src = Wa; dst = Wta; K = 1024; N = 3072; bx = j % 48; by = j / 48; }
  else           { const int j = bid - 4864; src = Wp; dst = Wtp; K = 1024; N = 1024; bx = j % 16; by = j / 16; }
  const int n0 = bx * 64, k0 = by * 64;
  #pragma unroll
  for (int it = 0; it < 4; it++){
    const int idx = it * 256 + tid;
    const int row = idx >> 4, c4 = (idx & 15) * 4;
    f32x4 v = *(const f32x4*)&src[(size_t)(k0 + row) * N + n0 + c4];
    #pragma unroll
    for (int j = 0; j < 4; j++) tile[row][c4 + j] = f2b(v[j]);
  }
  __syncthreads();
  const int r = tid >> 3, cc = (tid & 7) * 8;
  #pragma unroll
  for (int i = 0; i < 2; i++){
    const int rr = r + i * 32;
    u16x8 v;
    #pragma unroll
    for (int j = 0; j < 8; j++) v[j] = tile[cc + j][rr];
    *(u16x8*)&dst[(size_t)(n0 + rr) * K + k0 + cc] = v;
  }
}

// ================= QKV GEMM: 256x256 tile, BK=64, 8 waves (2Mx4N) =============
// 8-phase-class schedule (4 phases per K-tile, 2 K-tiles in LDS dbuf):
//   strided quadrants so each half-region's LDS reads finish early in the
//   group, allowing in-group prefetch of tile c+2 into the live slot.
// Counted vmcnt(4) once per K-tile (never drained to 0 in steady state).
// LDS swizzle (128B rows => full 3-bit XOR): logical 16B slot s at row r
// lives at physical slot s ^ (r & 7).  Applied on the global SOURCE for
// global_load_lds (linear dest) and on the ds_read address (rule 21).
// All fragment rows are == l15 (mod 8), so read-side XOR is (ks*4+l4)^(l15&7),
// constant per thread.  Round-1's 1-bit swizzle left an 8-way conflict
// (4.7M SQ_LDS_BANK_CONFLICT); this restores the conflict-free pattern the
// 128x128 kernel had (0 conflicts measured).

#define BARRIER() asm volatile("s_barrier" ::: "memory")
#define WAITV(N)  asm volatile("s_waitcnt vmcnt(" #N ")" ::: "memory")
#define WAITL0()  asm volatile("s_waitcnt lgkmcnt(0)" ::: "memory")

#define STAGE_A(KT, H) do{ \
  const size_t _g = (size_t)(H)*128*(size_t)Ktot + (size_t)(KT)*64; \
  char* _dst = ldsb + ((((KT)&1)*2+(H))<<14) + woff; \
  glds16(asrc0 + _g, _dst); \
  glds16(asrc1 + _g, _dst + 8192); \
}while(0)

#define STAGE_B(KT, H) do{ \
  const size_t _g = (size_t)(H)*128*(size_t)Ktot + (size_t)(KT)*64; \
  char* _dst = ldsb + 65536 + ((((KT)&1)*2+(H))<<14) + woff; \
  glds16(bsrc0 + _g, _dst); \
  glds16(bsrc1 + _g, _dst + 8192); \
}while(0)

#define LDA(D, QM) do{ \
  const char* _b = ldsb + (((D)*2+(QM))<<14) + arf; \
  _Pragma("unroll") \
  for (int mt = 0; mt < 4; mt++){ \
    af[mt][0] = *(const bf16x8*)(_b + mt*2048 + k0off); \
    af[mt][1] = *(const bf16x8*)(_b + mt*2048 + k1off); \
  } \
}while(0)

#define LDB(DST, D, QN) do{ \
  const char* _b = ldsb + 65536 + (((D)*2+(QN))<<14) + brf; \
  _Pragma("unroll") \
  for (int nt = 0; nt < 2; nt++){ \
    DST[nt][0] = *(const bf16x8*)(_b + nt*2048 + k0off); \
    DST[nt][1] = *(const bf16x8*)(_b + nt*2048 + k1off); \
  } \
}while(0)

#define MFMA_QUAD(QM, QN, BF) do{ \
  __builtin_amdgcn_s_setprio(1); \
  _Pragma("unroll") \
  for (int ks = 0; ks < 2; ks++){ \
    _Pragma("unroll") \
    for (int mt = 0; mt < 4; mt++){ \
      _Pragma("unroll") \
      for (int nt = 0; nt < 2; nt++){ \
        acc[QM][mt][QN][nt] = __builtin_amdgcn_mfma_f32_16x16x32_bf16( \
            af[mt][ks], BF[nt][ks], acc[QM][mt][QN][nt], 0, 0, 0); \
      } \
    } \
  } \
  __builtin_amdgcn_s_setprio(0); \
}while(0)

__global__ __launch_bounds__(512, 2) void gemm_qkv(
    const u16* __restrict__ A, const u16* __restrict__ Bt,
    const float* __restrict__ bias, u16* __restrict__ out, int Ktot)
{
  __shared__ __align__(16) char lds_s[131072];   // A: 4x16KB halves, B: same
  char* ldsb = lds_s;
  const int tid = threadIdx.x;
  const int lane = tid & 63, wave = tid >> 6;
  const int l15 = lane & 15, l4 = lane >> 4;
  const int wm = wave >> 2, wn = wave & 3;       // 2 M-waves x 4 N-waves
  const int m0 = blockIdx.y * 256, n0 = blockIdx.x * 256;
  const int NT = Ktot >> 6;                      // assumes NT >= 3
  const int woff = wave * 1024;

  // staging source precompute: phys 16B chunk P -> logical (row, col):
  //   row = P>>7, slot = ((P>>4)&7) ^ (row&7), col = slot*8 elems
  int grow0, gcol0, grow1, gcol1;
  { const int P = tid*16;        grow0 = P>>7; gcol0 = ((((P>>4)&7) ^ (grow0&7))<<3); }
  { const int P = 8192 + tid*16; grow1 = P>>7; gcol1 = ((((P>>4)&7) ^ (grow1&7))<<3); }
  const u16* asrc0 = A  + (size_t)(m0 + grow0)*Ktot + gcol0;
  const u16* asrc1 = A  + (size_t)(m0 + grow1)*Ktot + gcol1;
  const u16* bsrc0 = Bt + (size_t)(n0 + grow0)*Ktot + gcol0;
  const u16* bsrc1 = Bt + (size_t)(n0 + grow1)*Ktot + gcol1;

  // ds_read frag addressing: logical slot (ks*4+l4) at row rf; rf%8 == l15&7
  const int x7 = l15 & 7;
  const int k0off = ((l4 ^ x7)) * 16;            // ks=0
  const int k1off = k0off ^ 64;                  // ks=1: slot (4+l4)^x7
  const int arf = (wm*64 + l15) * 128;           // + mt*2048 per M-frag
  const int brf = (wn*32 + l15) * 128;           // + nt*2048 per N-frag

  f32x4 acc[2][4][2][2] = {};                    // [qm][mt][qn][nt]

  // prologue: tile0 (A0,B0,A1,B1) + tile1 (A0,B0) = 12 loads; keep last 4 in flight
  STAGE_A(0,0); STAGE_B(0,0); STAGE_A(0,1); STAGE_B(0,1);
  STAGE_A(1,0); STAGE_B(1,0);
  WAITV(4);
  BARRIER();

  for (int c = 0; c < NT; c++){
    const int d = c & 1;
    bf16x8 af[4][2], b0[2][2], b1[2][2];

    // phase 0: quad(0,0) -- reads A-half0,B-half0; stage A-half1(c+1)
    LDA(d, 0);
    LDB(b0, d, 0);
    if (c+1 < NT) STAGE_A(c+1, 1);
    BARRIER();
    WAITL0();
    MFMA_QUAD(0, 0, b0);
    BARRIER();

    // phase 1: quad(0,1) -- reads B-half1; stage B-half1(c+1)
    LDB(b1, d, 1);
    if (c+1 < NT) STAGE_B(c+1, 1);
    BARRIER();
    WAITL0();
    MFMA_QUAD(0, 1, b1);
    BARRIER();

    // phase 2: quad(1,0) -- reads A-half1; stage A-half0(c+2) (A-half0 reads done @p1 barrier)
    LDA(d, 1);
    if (c+2 < NT) STAGE_A(c+2, 0);
    BARRIER();
    WAITL0();
    MFMA_QUAD(1, 0, b0);
    BARRIER();

    // phase 3: quad(1,1) -- register-only; stage B-half0(c+2)
    if (c+2 < NT) STAGE_B(c+2, 0);
    BARRIER();
    MFMA_QUAD(1, 1, b1);
    // once-per-K-tile counted wait: tile c+1 fully landed, 4 newest loads may fly
    if (c == NT-2)      WAITV(0);
    else if (c < NT-2)  WAITV(4);
    BARRIER();
  }

  // ---------------- epilogue: qkv scatter ------------------------------------
  const int which = n0 >> 10;                    // uniform per block: 0=q,1=k,2=v
  #pragma unroll
  for (int qn = 0; qn < 2; qn++){
    #pragma unroll
    for (int nt = 0; nt < 2; nt++){
      const int n = n0 + qn*128 + wn*32 + nt*16 + l15;
      const float bias_v = bias[n];
      const int cc = n & 1023;
      const int h = cc >> 6, dd = cc & 63;
      if (which == 2){
        #pragma unroll
        for (int qm = 0; qm < 2; qm++){
          #pragma unroll
          for (int mt = 0; mt < 4; mt++){
            const int rowg = m0 + qm*128 + wm*64 + mt*16 + l4*4;
            const int bb = rowg >> 11, t = rowg & 2047;
            u16x4 pk;
            #pragma unroll
            for (int r = 0; r < 4; r++) pk[r] = f2b(acc[qm][mt][qn][nt][r] + bias_v);
            *(u16x4*)&out[(size_t)2*QS + ((size_t)(bb*NHEAD + h)*HD + dd)*T_SEQ + t] = pk;
          }
        }
      } else {
        const float sc = (which == 0) ? QSCALE : 1.0f;
        #pragma unroll
        for (int qm = 0; qm < 2; qm++){
          #pragma unroll
          for (int mt = 0; mt < 4; mt++){
            #pragma unroll
            for (int r = 0; r < 4; r++){
              const int rowg = m0 + qm*128 + wm*64 + mt*16 + l4*4 + r;
              const int bb = rowg >> 11, t = rowg & 2047;
              out[(size_t)which*QS + ((size_t)(bb*NHEAD + h)*T_SEQ + t)*HD + dd]
                  = f2b((acc[qm][mt][qn][nt][r] + bias_v) * sc);
            }
          }
        }
      }
    }
  }
}

// ---------------- GEMM (proj): A[M,K](bf16) * Bt[N,K]^T (+bias fp32) ---------
// fp32 [M,N] row-major (d_out). 128x128 tile, 4 waves.
__global__ __launch_bounds__(256) void gemm_proj(
    const u16* __restrict__ A, const u16* __restrict__ Bt,
    const float* __restrict__ bias, float* __restrict__ out, int Ktot)
{
  __shared__ __align__(16) u16 As[128*64];
  __shared__ __align__(16) u16 Bs[128*64];
  const int tid = threadIdx.x;
  const int lane = tid & 63, wave = tid >> 6;
  const int l15 = lane & 15, l4 = lane >> 4;
  const int wm = wave >> 1, wn = wave & 1;
  const int m0 = blockIdx.y * 128, n0 = blockIdx.x * 128;

  f32x4 acc[4][4] = {};

  for (int k0 = 0; k0 < Ktot; k0 += 64){
    #pragma unroll
    for (int ii = 0; ii < 4; ii++){
      const int slot0 = (wave*4 + ii) * 64;
      const int s = slot0 + lane;
      const int row = s >> 3;
      const int c = (s & 7) ^ (row & 7);
      glds16(&A [(size_t)(m0 + row) * Ktot + k0 + c*8], &As[slot0*8]);
      glds16(&Bt[(size_t)(n0 + row) * Ktot + k0 + c*8], &Bs[slot0*8]);
    }
    __syncthreads();
    #pragma unroll
    for (int ks = 0; ks < 2; ks++){
      bf16x8 af[4], bfr[4];
      #pragma unroll
      for (int mt = 0; mt < 4; mt++){
        const int rf = wm*64 + mt*16 + l15;
        const int slot = rf*8 + ((ks*4 + l4) ^ (rf & 7));
        af[mt] = *(const bf16x8*)&As[slot*8];
      }
      #pragma unroll
      for (int nt = 0; nt < 4; nt++){
        const int rf = wn*64 + nt*16 + l15;
        const int slot = rf*8 + ((ks*4 + l4) ^ (rf & 7));
        bfr[nt] = *(const bf16x8*)&Bs[slot*8];
      }
      #pragma unroll
      for (int mt = 0; mt < 4; mt++)
        #pragma unroll
        for (int nt = 0; nt < 4; nt++)
          acc[mt][nt] = __builtin_amdgcn_mfma_f32_16x16x32_bf16(
              af[mt], bfr[nt], acc[mt][nt], 0, 0, 0);
    }
    __syncthreads();
  }

  #pragma unroll
  for (int nt = 0; nt < 4; nt++){
    const int n = n0 + wn*64 + nt*16 + l15;
    const float bias_v = bias[n];
    #pragma unroll
    for (int mt = 0; mt < 4; mt++)
      #pragma unroll
      for (int r = 0; r < 4; r++){
        const int rowg = m0 + wm*64 + mt*16 + l4*4 + r;
        out[(size_t)rowg*CEMB + n] = acc[mt][nt][r] + bias_v;
      }
  }
}

// ---------------- causal flash attention, S^T, no-max softmax ----------------
__global__ __launch_bounds__(256, 4) void attn_kernel(
    const u16* __restrict__ qb, const u16* __restrict__ kb,
    const u16* __restrict__ vtb, u16* __restrict__ y)
{
  __shared__ __align__(16) u16 Ks[64*64];     // swizzled
  __shared__ __align__(16) u16 Vt[64*64];     // swizzled (V^T rows [d][t])
  __shared__ __align__(16) u16 Pw[8*16*72];   // per (wave,group) P[q][t]
  const int tid = threadIdx.x;
  const int lane = tid & 63, wave = tid >> 6;
  const int l15 = lane & 15, l4 = lane >> 4;
  const int qt = 15 - (blockIdx.x >> 6);      // longest-first
  const int bh = blockIdx.x & 63;
  const int q0 = qt * 128;
  const size_t base = (size_t)bh * (T_SEQ * HD);
  const u16* qp  = qb  + base;
  const u16* kp  = kb  + base;
  const u16* vtp = vtb + base;                // [hd][T]

  const int qmin0 = q0 + wave*32;
  const int qmin1 = qmin0 + 16;

  // Q as B-operand frags for both groups
  bf16x8 qf[2][2];
  #pragma unroll
  for (int g = 0; g < 2; g++){
    const int m = qmin0 + g*16 + l15;
    qf[g][0] = *(const bf16x8*)&qp[m*HD +      l4*8];
    qf[g][1] = *(const bf16x8*)&qp[m*HD + 32 + l4*8];
  }
  f32x4 o[2][4] = {};
  float l_run[2] = {0.f, 0.f};

  const int s0i = (wave*2 + 0) * 64 + lane;
  const int s1i = (wave*2 + 1) * 64 + lane;
  const int row0 = s0i >> 3, c0 = (s0i & 7) ^ (row0 & 7);
  const int row1 = s1i >> 3, c1 = (s1i & 7) ^ (row1 & 7);
  const int koff0 = row0*HD + c0*8, koff1 = row1*HD + c1*8;
  const int voff0 = row0*T_SEQ + c0*8, voff1 = row1*T_SEQ + c1*8;
  const int ldso0 = (wave*2 + 0) * 64 * 8, ldso1 = (wave*2 + 1) * 64 * 8;

  const int nkt = 2*qt + 2;
  for (int kt = 0; kt < nkt; kt++){
    __syncthreads();                          // prior tile's LDS reads done
    glds16(&kp [kt*4096 + koff0], &Ks[ldso0]);
    glds16(&kp [kt*4096 + koff1], &Ks[ldso1]);
    glds16(&vtp[kt*64   + voff0], &Vt[ldso0]);
    glds16(&vtp[kt*64   + voff1], &Vt[ldso1]);
    __syncthreads();                          // staged (barrier drains vmcnt)

    const int t0 = kt*64;
    if (t0 <= qmin1 + 15){                    // wave-uniform
      const bool act0 = (t0 <= qmin0 + 15);

      // S^T = K·Q^T for both groups, sharing each K fragment read
      f32x4 s0[4], s1[4];
      #pragma unroll
      for (int nb = 0; nb < 4; nb++){
        f32x4 a0 = {}, a1 = {};
        #pragma unroll
        for (int ks = 0; ks < 2; ks++){
          const int rf = nb*16 + l15;
          const int slot = rf*8 + ((ks*4 + l4) ^ (rf & 7));
          bf16x8 kf = *(const bf16x8*)&Ks[slot*8];
          a1 = __builtin_amdgcn_mfma_f32_16x16x32_bf16(kf, qf[1][ks], a1, 0, 0, 0);
          if (act0)
            a0 = __builtin_amdgcn_mfma_f32_16x16x32_bf16(kf, qf[0][ks], a0, 0, 0, 0);
        }
        s1[nb] = a1; s0[nb] = a0;
      }

      // softmax (exp2 domain, no max tracking) + P write, per group
      #pragma unroll
      for (int g = 0; g < 2; g++){
        if (g == 0 && !act0) continue;
        f32x4* sf = (g == 0) ? s0 : s1;
        const int qmin = (g == 0) ? qmin0 : qmin1;
        const int qg = qmin + l15;
        float lsum = 0.f;
        if (t0 + 63 > qmin){                  // diagonal-region tile: mask
          #pragma unroll
          for (int nb = 0; nb < 4; nb++){
            u16x4 pk;
            #pragma unroll
            for (int r = 0; r < 4; r++){
              const int t = t0 + nb*16 + l4*4 + r;
              float p = __builtin_amdgcn_exp2f(sf[nb][r]);
              p = (t <= qg) ? p : 0.0f;
              lsum += p;
              pk[r] = f2b(p);
            }
            *(u16x4*)&Pw[(wave*2 + g)*1152 + l15*72 + nb*16 + l4*4] = pk;
          }
        } else {
          #pragma unroll
          for (int nb = 0; nb < 4; nb++){
            u16x4 pk;
            #pragma unroll
            for (int r = 0; r < 4; r++){
              const float p = __builtin_amdgcn_exp2f(sf[nb][r]);
              lsum += p;
              pk[r] = f2b(p);
            }
            *(u16x4*)&Pw[(wave*2 + g)*1152 + l15*72 + nb*16 + l4*4] = pk;
          }
        }
        l_run[g] += lsum;
      }

      // O^T += V^T·P^T, sharing each V fragment read between groups
      #pragma unroll
      for (int ks = 0; ks < 2; ks++){
        bf16x8 pf1 = *(const bf16x8*)&Pw[(wave*2 + 1)*1152 + l15*72 + ks*32 + l4*8];
        bf16x8 pf0;
        if (act0) pf0 = *(const bf16x8*)&Pw[(wave*2 + 0)*1152 + l15*72 + ks*32 + l4*8];
        #pragma unroll
        for (int nh = 0; nh < 4; nh++){
          const int rf = nh*16 + l15;
          const int slot = rf*8 + ((ks*4 + l4) ^ (rf & 7));
          bf16x8 vf = *(const bf16x8*)&Vt[slot*8];
          o[1][nh] = __builtin_amdgcn_mfma_f32_16x16x32_bf16(vf, pf1, o[1][nh], 0, 0, 0);
          if (act0)
            o[0][nh] = __builtin_amdgcn_mfma_f32_16x16x32_bf16(vf, pf0, o[0][nh], 0, 0, 0);
        }
      }
    }
  }

  // epilogue per group: O^T[d][q]; lane q = l15; d = nh*16 + l4*4 + r
  const int b = bh >> 4, h = bh & 15;
  #pragma unroll
  for (int g = 0; g < 2; g++){
    float lr = l_run[g];
    lr += __shfl_xor(lr, 16);
    lr += __shfl_xor(lr, 32);
    const float inv_l = 1.0f / lr;
    const int t = qmin0 + g*16 + l15;
    #pragma unroll
    for (int nh = 0; nh < 4; nh++){
      u16x4 pk;
      #pragma unroll
      for (int r = 0; r < 4; r++) pk[r] = f2b(o[g][nh][r] * inv_l);
      *(u16x4*)&y[((size_t)(b*T_SEQ + t))*CEMB + h*HD + nh*16 + l4*4] = pk;
    }
  }
}

extern "C" void kernel_launch(void* const* d_in, const int* in_sizes, int n_in,
                              void* d_out, int out_size, void* d_ws, size_t ws_size,
                              hipStream_t stream) {
  const float* x      = (const float*)d_in[0];
  const float* W_attn = (const float*)d_in[1];
  const float* b_attn = (const float*)d_in[2];
  const float* W_proj = (const float*)d_in[3];
  const float* b_proj = (const float*)d_in[4];
  float* out = (float*)d_out;
  u16* ws  = (u16*)d_ws;

  u16* Wt_attn = ws;                 // 3,145,728
  u16* Wt_proj = ws + 3145728;       // 1,048,576
  u16* xb      = ws + 4194304;       // 8,388,608 (x as bf16; reused as y)
  u16* qkv     = ws + 12582912;      // 3 * QS
  u16* y       = xb;                 // xb dead after QKV GEMM

  prep_kernel<<<5120, 256, 0, stream>>>(x, xb, W_attn, Wt_attn, W_proj, Wt_proj);
  gemm_qkv<<<dim3(12, 32), 512, 0, stream>>>(xb, Wt_attn, b_attn, qkv, 1024);
  attn_kernel<<<1024, 256, 0, stream>>>(qkv, qkv + QS, qkv + 2*QS, y);
  gemm_proj<<<dim3(8, 64), 256, 0, stream>>>(y, Wt_proj, b_proj, out, 1024);
}

// Round 4
// 238.089 us; speedup vs baseline: 1.0623x; 1.0340x over previous
//
#include <hip/hip_runtime.h>
#include <stdint.h>

typedef unsigned short u16;
typedef __bf16 bf16;
typedef bf16 bf16x8 __attribute__((ext_vector_type(8)));
typedef float f32x4 __attribute__((ext_vector_type(4)));
typedef u16 u16x8 __attribute__((ext_vector_type(8)));
typedef u16 u16x4 __attribute__((ext_vector_type(4)));

#define T_SEQ 2048
#define NHEAD 16
#define HD    64
#define CEMB  1024
#define QS    8388608   // elems per q/k/v tensor: 4*16*2048*64
#define QSCALE 0.18033688011112042f   // 0.125 * log2(e); softmax in exp2 domain

#define BARRIER() asm volatile("s_barrier" ::: "memory")
#define WAITV(N)  asm volatile("s_waitcnt vmcnt(" #N ")" ::: "memory")

__device__ __forceinline__ u16 f2b(float f){
  bf16 h = (bf16)f;
  return __builtin_bit_cast(u16, h);
}
__device__ __forceinline__ void glds16(const void* g, const void* l){
  __builtin_amdgcn_global_load_lds(
    (__attribute__((address_space(1))) unsigned int*)(uintptr_t)g,
    (__attribute__((address_space(3))) unsigned int*)(uintptr_t)l,
    16, 0, 0);
}

// -------- fused prep: x fp32->bf16 (4096 blocks), W_attn T (768), W_proj T (256)
__global__ __launch_bounds__(256) void prep_kernel(
    const float* __restrict__ x, u16* __restrict__ xb,
    const float* __restrict__ Wa, u16* __restrict__ Wta,
    const float* __restrict__ Wp, u16* __restrict__ Wtp)
{
  __shared__ __align__(16) u16 tile[64][72];
  const int bid = blockIdx.x;
  const int tid = threadIdx.x;
  if (bid < 4096){
    const int i = (bid * 256 + tid) * 8;
    f32x4 a = *(const f32x4*)&x[i];
    f32x4 b = *(const f32x4*)&x[i + 4];
    u16x8 h;
    #pragma unroll
    for (int j = 0; j < 4; j++){ h[j] = f2b(a[j]); h[4+j] = f2b(b[j]); }
    *(u16x8*)&xb[i] = h;
    return;
  }
  const float* src; u16* dst; int K, N, bx, by;
  if (bid < 4864){ const int j = bid - 4096; src = Wa; dst = Wta; K = 1024; N = 3072; bx = j % 48; by = j / 48; }
  else           { const int j = bid - 4864; src = Wp; dst = Wtp; K = 1024; N = 1024; bx = j % 16; by = j / 16; }
  const int n0 = bx * 64, k0 = by * 64;
  #pragma unroll
  for (int it = 0; it < 4; it++){
    const int idx = it * 256 + tid;
    const int row = idx >> 4, c4 = (idx & 15) * 4;
    f32x4 v = *(const f32x4*)&src[(size_t)(k0 + row) * N + n0 + c4];
    #pragma unroll
    for (int j = 0; j < 4; j++) tile[row][c4 + j] = f2b(v[j]);
  }
  __syncthreads();
  const int r = tid >> 3, cc = (tid & 7) * 8;
  #pragma unroll
  for (int i = 0; i < 2; i++){
    const int rr = r + i * 32;
    u16x8 v;
    #pragma unroll
    for (int j = 0; j < 8; j++) v[j] = tile[cc + j][rr];
    *(u16x8*)&dst[(size_t)(n0 + rr) * K + k0 + cc] = v;
  }
}

// ---------------- QKV GEMM (restored round-0 structure, 66 us known-good) ----
// A[M,K](bf16) * Bt[N,K]^T (+bias fp32) -> qkv scatter (bf16):
//   q (pre-scaled by QSCALE), k -> [B,H,T,hd]; v -> [B,H,hd,T] transposed.
// 128x128 tile, 4 waves, grid 24x64 = 1536 blocks = 6 exact rounds,
// 5 blocks/CU resident (32KB LDS) -> inter-block overlap hides the
// per-tile vmcnt drain (m114).  K=1024 caps deeper pipelines at ~850 TF
// (m248), so this stays within ~8% of the measured shape ceiling.
__global__ __launch_bounds__(256) void gemm_qkv128(
    const u16* __restrict__ A, const u16* __restrict__ Bt,
    const float* __restrict__ bias, u16* __restrict__ out, int Ktot)
{
  __shared__ __align__(16) u16 As[128*64];
  __shared__ __align__(16) u16 Bs[128*64];
  const int tid = threadIdx.x;
  const int lane = tid & 63, wave = tid >> 6;
  const int l15 = lane & 15, l4 = lane >> 4;
  const int wm = wave >> 1, wn = wave & 1;
  const int m0 = blockIdx.y * 128, n0 = blockIdx.x * 128;

  f32x4 acc[4][4] = {};

  for (int k0 = 0; k0 < Ktot; k0 += 64){
    #pragma unroll
    for (int ii = 0; ii < 4; ii++){
      const int slot0 = (wave*4 + ii) * 64;
      const int s = slot0 + lane;
      const int row = s >> 3;
      const int c = (s & 7) ^ (row & 7);
      glds16(&A [(size_t)(m0 + row) * Ktot + k0 + c*8], &As[slot0*8]);
      glds16(&Bt[(size_t)(n0 + row) * Ktot + k0 + c*8], &Bs[slot0*8]);
    }
    __syncthreads();
    #pragma unroll
    for (int ks = 0; ks < 2; ks++){
      bf16x8 af[4], bfr[4];
      #pragma unroll
      for (int mt = 0; mt < 4; mt++){
        const int rf = wm*64 + mt*16 + l15;
        const int slot = rf*8 + ((ks*4 + l4) ^ (rf & 7));
        af[mt] = *(const bf16x8*)&As[slot*8];
      }
      #pragma unroll
      for (int nt = 0; nt < 4; nt++){
        const int rf = wn*64 + nt*16 + l15;
        const int slot = rf*8 + ((ks*4 + l4) ^ (rf & 7));
        bfr[nt] = *(const bf16x8*)&Bs[slot*8];
      }
      #pragma unroll
      for (int mt = 0; mt < 4; mt++)
        #pragma unroll
        for (int nt = 0; nt < 4; nt++)
          acc[mt][nt] = __builtin_amdgcn_mfma_f32_16x16x32_bf16(
              af[mt], bfr[nt], acc[mt][nt], 0, 0, 0);
    }
    __syncthreads();
  }

  #pragma unroll
  for (int nt = 0; nt < 4; nt++){
    const int n = n0 + wn*64 + nt*16 + l15;
    const float bias_v = bias[n];
    const int which = n >> 10;
    const int cc = n & 1023;
    const int h = cc >> 6, d = cc & 63;
    const float sc = (which == 0) ? QSCALE : 1.0f;
    if (which == 2){
      #pragma unroll
      for (int mt = 0; mt < 4; mt++){
        const int rowg = m0 + wm*64 + mt*16 + l4*4;
        const int bb = rowg >> 11, t = rowg & 2047;
        u16x4 pk;
        #pragma unroll
        for (int r = 0; r < 4; r++) pk[r] = f2b(acc[mt][nt][r] + bias_v);
        *(u16x4*)&out[(size_t)2*QS + ((size_t)(bb*NHEAD + h)*HD + d)*T_SEQ + t] = pk;
      }
    } else {
      #pragma unroll
      for (int mt = 0; mt < 4; mt++)
        #pragma unroll
        for (int r = 0; r < 4; r++){
          const int rowg = m0 + wm*64 + mt*16 + l4*4 + r;
          const int bb = rowg >> 11, t = rowg & 2047;
          out[(size_t)which*QS + ((size_t)(bb*NHEAD + h)*T_SEQ + t)*HD + d]
              = f2b((acc[mt][nt][r] + bias_v) * sc);
        }
    }
  }
}

// ---------------- GEMM (proj): A[M,K](bf16) * Bt[N,K]^T (+bias fp32) ---------
// fp32 [M,N] row-major (d_out). 128x128 tile, 4 waves.
__global__ __launch_bounds__(256) void gemm_proj(
    const u16* __restrict__ A, const u16* __restrict__ Bt,
    const float* __restrict__ bias, float* __restrict__ out, int Ktot)
{
  __shared__ __align__(16) u16 As[128*64];
  __shared__ __align__(16) u16 Bs[128*64];
  const int tid = threadIdx.x;
  const int lane = tid & 63, wave = tid >> 6;
  const int l15 = lane & 15, l4 = lane >> 4;
  const int wm = wave >> 1, wn = wave & 1;
  const int m0 = blockIdx.y * 128, n0 = blockIdx.x * 128;

  f32x4 acc[4][4] = {};

  for (int k0 = 0; k0 < Ktot; k0 += 64){
    #pragma unroll
    for (int ii = 0; ii < 4; ii++){
      const int slot0 = (wave*4 + ii) * 64;
      const int s = slot0 + lane;
      const int row = s >> 3;
      const int c = (s & 7) ^ (row & 7);
      glds16(&A [(size_t)(m0 + row) * Ktot + k0 + c*8], &As[slot0*8]);
      glds16(&Bt[(size_t)(n0 + row) * Ktot + k0 + c*8], &Bs[slot0*8]);
    }
    __syncthreads();
    #pragma unroll
    for (int ks = 0; ks < 2; ks++){
      bf16x8 af[4], bfr[4];
      #pragma unroll
      for (int mt = 0; mt < 4; mt++){
        const int rf = wm*64 + mt*16 + l15;
        const int slot = rf*8 + ((ks*4 + l4) ^ (rf & 7));
        af[mt] = *(const bf16x8*)&As[slot*8];
      }
      #pragma unroll
      for (int nt = 0; nt < 4; nt++){
        const int rf = wn*64 + nt*16 + l15;
        const int slot = rf*8 + ((ks*4 + l4) ^ (rf & 7));
        bfr[nt] = *(const bf16x8*)&Bs[slot*8];
      }
      #pragma unroll
      for (int mt = 0; mt < 4; mt++)
        #pragma unroll
        for (int nt = 0; nt < 4; nt++)
          acc[mt][nt] = __builtin_amdgcn_mfma_f32_16x16x32_bf16(
              af[mt], bfr[nt], acc[mt][nt], 0, 0, 0);
    }
    __syncthreads();
  }

  #pragma unroll
  for (int nt = 0; nt < 4; nt++){
    const int n = n0 + wn*64 + nt*16 + l15;
    const float bias_v = bias[n];
    #pragma unroll
    for (int mt = 0; mt < 4; mt++)
      #pragma unroll
      for (int r = 0; r < 4; r++){
        const int rowg = m0 + wm*64 + mt*16 + l4*4 + r;
        out[(size_t)rowg*CEMB + n] = acc[mt][nt][r] + bias_v;
      }
  }
}

// ---------------- causal flash attention, S^T, no-max softmax ----------------
// K/V double-buffered with counted vmcnt.  Stage tile kt+1 while computing kt;
// each wave drains only its OWN tile-kt loads (WAITV(4)) before the barrier --
// barrier release then guarantees ALL waves' kt data landed, while kt+1's 4
// loads stay in flight across the barrier.  Removes the per-tile full
// vmcnt(0) drain from the critical path.
// LDS: 2x(8KB K + 8KB V) + 18KB P = 50KB -> 3 blocks/CU.
__global__ __launch_bounds__(256, 3) void attn_kernel(
    const u16* __restrict__ qb, const u16* __restrict__ kb,
    const u16* __restrict__ vtb, u16* __restrict__ y)
{
  __shared__ __align__(16) u16 Ks[2*64*64];   // swizzled, double-buffered
  __shared__ __align__(16) u16 Vt[2*64*64];   // swizzled (V^T rows [d][t])
  __shared__ __align__(16) u16 Pw[8*16*72];   // per (wave,group) P[q][t]
  const int tid = threadIdx.x;
  const int lane = tid & 63, wave = tid >> 6;
  const int l15 = lane & 15, l4 = lane >> 4;
  const int qt = 15 - (blockIdx.x >> 6);      // longest-first
  const int bh = blockIdx.x & 63;
  const int q0 = qt * 128;
  const size_t base = (size_t)bh * (T_SEQ * HD);
  const u16* qp  = qb  + base;
  const u16* kp  = kb  + base;
  const u16* vtp = vtb + base;                // [hd][T]

  const int qmin0 = q0 + wave*32;
  const int qmin1 = qmin0 + 16;

  // Q as B-operand frags for both groups
  bf16x8 qf[2][2];
  #pragma unroll
  for (int g = 0; g < 2; g++){
    const int m = qmin0 + g*16 + l15;
    qf[g][0] = *(const bf16x8*)&qp[m*HD +      l4*8];
    qf[g][1] = *(const bf16x8*)&qp[m*HD + 32 + l4*8];
  }
  f32x4 o[2][4] = {};
  float l_run[2] = {0.f, 0.f};

  // staging addresses (constant per thread): 2 chunks each for K and V
  const int s0i = (wave*2 + 0) * 64 + lane;
  const int s1i = (wave*2 + 1) * 64 + lane;
  const int row0 = s0i >> 3, c0 = (s0i & 7) ^ (row0 & 7);
  const int row1 = s1i >> 3, c1 = (s1i & 7) ^ (row1 & 7);
  const int koff0 = row0*HD + c0*8, koff1 = row1*HD + c1*8;
  const int voff0 = row0*T_SEQ + c0*8, voff1 = row1*T_SEQ + c1*8;
  const int ldso0 = (wave*2 + 0) * 64 * 8, ldso1 = (wave*2 + 1) * 64 * 8;

  const int nkt = 2*qt + 2;

  // prologue: stage tile 0 into buffer 0
  glds16(&kp [koff0], &Ks[ldso0]);
  glds16(&kp [koff1], &Ks[ldso1]);
  glds16(&vtp[voff0], &Vt[ldso0]);
  glds16(&vtp[voff1], &Vt[ldso1]);

  for (int kt = 0; kt < nkt; kt++){
    const int cb = (kt & 1) * 4096;           // current LDS buffer (u16 elems)
    if (kt + 1 < nkt){
      const int nb = ((kt + 1) & 1) * 4096;   // next buffer
      glds16(&kp [(kt+1)*4096 + koff0], &Ks[nb + ldso0]);
      glds16(&kp [(kt+1)*4096 + koff1], &Ks[nb + ldso1]);
      glds16(&vtp[(kt+1)*64   + voff0], &Vt[nb + ldso0]);
      glds16(&vtp[(kt+1)*64   + voff1], &Vt[nb + ldso1]);
      WAITV(4);                               // own tile-kt loads landed
    } else {
      WAITV(0);
    }
    BARRIER();                                // => every wave's kt data landed

    const int t0 = kt*64;
    if (t0 <= qmin1 + 15){                    // wave-uniform
      const bool act0 = (t0 <= qmin0 + 15);

      // S^T = K·Q^T for both groups, sharing each K fragment read
      f32x4 s0[4], s1[4];
      #pragma unroll
      for (int nb2 = 0; nb2 < 4; nb2++){
        f32x4 a0 = {}, a1 = {};
        #pragma unroll
        for (int ks = 0; ks < 2; ks++){
          const int rf = nb2*16 + l15;
          const int slot = rf*8 + ((ks*4 + l4) ^ (rf & 7));
          bf16x8 kf = *(const bf16x8*)&Ks[cb + slot*8];
          a1 = __builtin_amdgcn_mfma_f32_16x16x32_bf16(kf, qf[1][ks], a1, 0, 0, 0);
          if (act0)
            a0 = __builtin_amdgcn_mfma_f32_16x16x32_bf16(kf, qf[0][ks], a0, 0, 0, 0);
        }
        s1[nb2] = a1; s0[nb2] = a0;
      }

      // softmax (exp2 domain, no max tracking) + P write, per group
      #pragma unroll
      for (int g = 0; g < 2; g++){
        if (g == 0 && !act0) continue;
        f32x4* sf = (g == 0) ? s0 : s1;
        const int qmin = (g == 0) ? qmin0 : qmin1;
        const int qg = qmin + l15;
        float lsum = 0.f;
        if (t0 + 63 > qmin){                  // diagonal-region tile: mask
          #pragma unroll
          for (int nb2 = 0; nb2 < 4; nb2++){
            u16x4 pk;
            #pragma unroll
            for (int r = 0; r < 4; r++){
              const int t = t0 + nb2*16 + l4*4 + r;
              float p = __builtin_amdgcn_exp2f(sf[nb2][r]);
              p = (t <= qg) ? p : 0.0f;
              lsum += p;
              pk[r] = f2b(p);
            }
            *(u16x4*)&Pw[(wave*2 + g)*1152 + l15*72 + nb2*16 + l4*4] = pk;
          }
        } else {
          #pragma unroll
          for (int nb2 = 0; nb2 < 4; nb2++){
            u16x4 pk;
            #pragma unroll
            for (int r = 0; r < 4; r++){
              const float p = __builtin_amdgcn_exp2f(sf[nb2][r]);
              lsum += p;
              pk[r] = f2b(p);
            }
            *(u16x4*)&Pw[(wave*2 + g)*1152 + l15*72 + nb2*16 + l4*4] = pk;
          }
        }
        l_run[g] += lsum;
      }

      // O^T += V^T·P^T, sharing each V fragment read between groups
      #pragma unroll
      for (int ks = 0; ks < 2; ks++){
        bf16x8 pf1 = *(const bf16x8*)&Pw[(wave*2 + 1)*1152 + l15*72 + ks*32 + l4*8];
        bf16x8 pf0;
        if (act0) pf0 = *(const bf16x8*)&Pw[(wave*2 + 0)*1152 + l15*72 + ks*32 + l4*8];
        #pragma unroll
        for (int nh = 0; nh < 4; nh++){
          const int rf = nh*16 + l15;
          const int slot = rf*8 + ((ks*4 + l4) ^ (rf & 7));
          bf16x8 vf = *(const bf16x8*)&Vt[cb + slot*8];
          o[1][nh] = __builtin_amdgcn_mfma_f32_16x16x32_bf16(vf, pf1, o[1][nh], 0, 0, 0);
          if (act0)
            o[0][nh] = __builtin_amdgcn_mfma_f32_16x16x32_bf16(vf, pf0, o[0][nh], 0, 0, 0);
        }
      }
    }
    BARRIER();                                // reads done before buffer reuse
  }

  // epilogue per group: O^T[d][q]; lane q = l15; d = nh*16 + l4*4 + r
  const int b = bh >> 4, h = bh & 15;
  #pragma unroll
  for (int g = 0; g < 2; g++){
    float lr = l_run[g];
    lr += __shfl_xor(lr, 16);
    lr += __shfl_xor(lr, 32);
    const float inv_l = 1.0f / lr;
    const int t = qmin0 + g*16 + l15;
    #pragma unroll
    for (int nh = 0; nh < 4; nh++){
      u16x4 pk;
      #pragma unroll
      for (int r = 0; r < 4; r++) pk[r] = f2b(o[g][nh][r] * inv_l);
      *(u16x4*)&y[((size_t)(b*T_SEQ + t))*CEMB + h*HD + nh*16 + l4*4] = pk;
    }
  }
}

extern "C" void kernel_launch(void* const* d_in, const int* in_sizes, int n_in,
                              void* d_out, int out_size, void* d_ws, size_t ws_size,
                              hipStream_t stream) {
  const float* x      = (const float*)d_in[0];
  const float* W_attn = (const float*)d_in[1];
  const float* b_attn = (const float*)d_in[2];
  const float* W_proj = (const float*)d_in[3];
  const float* b_proj = (const float*)d_in[4];
  float* out = (float*)d_out;
  u16* ws  = (u16*)d_ws;

  u16* Wt_attn = ws;                 // 3,145,728
  u16* Wt_proj = ws + 3145728;       // 1,048,576
  u16* xb      = ws + 4194304;       // 8,388,608 (x as bf16; reused as y)
  u16* qkv     = ws + 12582912;      // 3 * QS
  u16* y       = xb;                 // xb dead after QKV GEMM

  prep_kernel<<<5120, 256, 0, stream>>>(x, xb, W_attn, Wt_attn, W_proj, Wt_proj);
  gemm_qkv128<<<dim3(24, 64), 256, 0, stream>>>(xb, Wt_attn, b_attn, qkv, 1024);
  attn_kernel<<<1024, 256, 0, stream>>>(qkv, qkv + QS, qkv + 2*QS, y);
  gemm_proj<<<dim3(8, 64), 256, 0, stream>>>(y, Wt_proj, b_proj, out, 1024);
}

// Round 6
// 226.862 us; speedup vs baseline: 1.1149x; 1.0495x over previous
//
#include <hip/hip_runtime.h>
#include <stdint.h>

typedef unsigned short u16;
typedef __bf16 bf16;
typedef bf16 bf16x8 __attribute__((ext_vector_type(8)));
typedef float f32x4 __attribute__((ext_vector_type(4)));
typedef u16 u16x8 __attribute__((ext_vector_type(8)));
typedef u16 u16x4 __attribute__((ext_vector_type(4)));

#define T_SEQ 2048
#define NHEAD 16
#define HD    64
#define CEMB  1024
#define QS    8388608   // elems per q/k/v tensor: 4*16*2048*64
#define QSCALE 0.18033688011112042f   // 0.125 * log2(e); softmax in exp2 domain

#define BARRIER() asm volatile("s_barrier" ::: "memory")
#define WAITV(N)  asm volatile("s_waitcnt vmcnt(" #N ")" ::: "memory")

__device__ __forceinline__ u16 f2b(float f){
  bf16 h = (bf16)f;
  return __builtin_bit_cast(u16, h);
}
__device__ __forceinline__ void glds16(const void* g, const void* l){
  __builtin_amdgcn_global_load_lds(
    (__attribute__((address_space(1))) unsigned int*)(uintptr_t)g,
    (__attribute__((address_space(3))) unsigned int*)(uintptr_t)l,
    16, 0, 0);
}

// -------- fused prep: x fp32->bf16 (4096 blocks), W_attn T (768), W_proj T (256)
__global__ __launch_bounds__(256) void prep_kernel(
    const float* __restrict__ x, u16* __restrict__ xb,
    const float* __restrict__ Wa, u16* __restrict__ Wta,
    const float* __restrict__ Wp, u16* __restrict__ Wtp)
{
  __shared__ __align__(16) u16 tile[64][72];
  const int bid = blockIdx.x;
  const int tid = threadIdx.x;
  if (bid < 4096){
    const int i = (bid * 256 + tid) * 8;
    f32x4 a = *(const f32x4*)&x[i];
    f32x4 b = *(const f32x4*)&x[i + 4];
    u16x8 h;
    #pragma unroll
    for (int j = 0; j < 4; j++){ h[j] = f2b(a[j]); h[4+j] = f2b(b[j]); }
    *(u16x8*)&xb[i] = h;
    return;
  }
  const float* src; u16* dst; int K, N, bx, by;
  if (bid < 4864){ const int j = bid - 4096; src = Wa; dst = Wta; K = 1024; N = 3072; bx = j % 48; by = j / 48; }
  else           { const int j = bid - 4864; src = Wp; dst = Wtp; K = 1024; N = 1024; bx = j % 16; by = j / 16; }
  const int n0 = bx * 64, k0 = by * 64;
  #pragma unroll
  for (int it = 0; it < 4; it++){
    const int idx = it * 256 + tid;
    const int row = idx >> 4, c4 = (idx & 15) * 4;
    f32x4 v = *(const f32x4*)&src[(size_t)(k0 + row) * N + n0 + c4];
    #pragma unroll
    for (int j = 0; j < 4; j++) tile[row][c4 + j] = f2b(v[j]);
  }
  __syncthreads();
  const int r = tid >> 3, cc = (tid & 7) * 8;
  #pragma unroll
  for (int i = 0; i < 2; i++){
    const int rr = r + i * 32;
    u16x8 v;
    #pragma unroll
    for (int j = 0; j < 8; j++) v[j] = tile[cc + j][rr];
    *(u16x8*)&dst[(size_t)(n0 + rr) * K + k0 + cc] = v;
  }
}

// ---------------- QKV GEMM: 128x128 tile + dbuf counted-vmcnt + XCD swizzle --
// A[M,K](bf16) * Bt[N,K]^T (+bias fp32) -> qkv scatter (bf16):
//   q (pre-scaled by QSCALE), k -> [B,H,T,hd]; v -> [B,H,hd,T] transposed.
// (1) LDS double-buffer with counted vmcnt (attn-proven pattern): each
// wave issues tile c+1's 8 glds, then WAITV(8) drains only its OWN tile-c
// loads; barrier release => all waves' tile-c data landed while c+1's loads
// stay in flight across the barrier (kills the m97 vmcnt(0)-drain stall).
// LDS 64KB -> still 2 blocks/CU (measured occupancy was 2 anyway).
// (2) bijective XCD swizzle (m204): 64 resident blocks per XCD get
// consecutive tiles -> 3 A-panels (0.75MB) + shared B sweep fit 4MB L2
// (was ~21 A-panels = 5.3MB -> thrash -> FETCH 71.8MB vs 23MB ideal).
#define QSTAGE(BUF, K0) do{ \
  _Pragma("unroll") \
  for (int ii = 0; ii < 4; ii++){ \
    const int slot0 = (wave*4 + ii) * 64; \
    const int s = slot0 + lane; \
    const int row = s >> 3; \
    const int cc8 = ((s & 7) ^ (row & 7)) * 8; \
    glds16(&A [(size_t)(m0 + row) * Ktot + (K0) + cc8], &As[BUF][slot0*8]); \
    glds16(&Bt[(size_t)(n0 + row) * Ktot + (K0) + cc8], &Bs[BUF][slot0*8]); \
  } \
}while(0)

__global__ __launch_bounds__(256) void gemm_qkv128(
    const u16* __restrict__ A, const u16* __restrict__ Bt,
    const float* __restrict__ bias, u16* __restrict__ out, int Ktot)
{
  __shared__ __align__(16) u16 As[2][128*64];
  __shared__ __align__(16) u16 Bs[2][128*64];
  const int tid = threadIdx.x;
  const int lane = tid & 63, wave = tid >> 6;
  const int l15 = lane & 15, l4 = lane >> 4;
  const int wm = wave >> 1, wn = wave & 1;
  // bijective XCD swizzle: 1536 blocks, 8 XCDs, 192 per XCD
  const int id = blockIdx.x;
  const int swz = (id & 7) * 192 + (id >> 3);
  const int m0 = (swz / 24) * 128, n0 = (swz % 24) * 128;
  const int NT = Ktot >> 6;

  f32x4 acc[4][4] = {};

  QSTAGE(0, 0);                                // prologue: tile 0 -> buf 0
  for (int c = 0; c < NT; c++){
    const int cur = c & 1;
    if (c + 1 < NT){
      QSTAGE(cur ^ 1, (c + 1) * 64);           // 8 more in flight (16 total)
      WAITV(8);                                // own tile-c loads landed
    } else {
      WAITV(0);
    }
    BARRIER();                                 // => all waves' tile-c landed

    #pragma unroll
    for (int ks = 0; ks < 2; ks++){
      bf16x8 af[4], bfr[4];
      #pragma unroll
      for (int mt = 0; mt < 4; mt++){
        const int rf = wm*64 + mt*16 + l15;
        const int slot = rf*8 + ((ks*4 + l4) ^ (rf & 7));
        af[mt] = *(const bf16x8*)&As[cur][slot*8];
      }
      #pragma unroll
      for (int nt = 0; nt < 4; nt++){
        const int rf = wn*64 + nt*16 + l15;
        const int slot = rf*8 + ((ks*4 + l4) ^ (rf & 7));
        bfr[nt] = *(const bf16x8*)&Bs[cur][slot*8];
      }
      #pragma unroll
      for (int mt = 0; mt < 4; mt++)
        #pragma unroll
        for (int nt = 0; nt < 4; nt++)
          acc[mt][nt] = __builtin_amdgcn_mfma_f32_16x16x32_bf16(
              af[mt], bfr[nt], acc[mt][nt], 0, 0, 0);
    }
    BARRIER();                                 // reads done before overwrite
  }

  #pragma unroll
  for (int nt = 0; nt < 4; nt++){
    const int n = n0 + wn*64 + nt*16 + l15;
    const float bias_v = bias[n];
    const int which = n >> 10;
    const int cc = n & 1023;
    const int h = cc >> 6, d = cc & 63;
    const float sc = (which == 0) ? QSCALE : 1.0f;
    if (which == 2){
      #pragma unroll
      for (int mt = 0; mt < 4; mt++){
        const int rowg = m0 + wm*64 + mt*16 + l4*4;
        const int bb = rowg >> 11, t = rowg & 2047;
        u16x4 pk;
        #pragma unroll
        for (int r = 0; r < 4; r++) pk[r] = f2b(acc[mt][nt][r] + bias_v);
        *(u16x4*)&out[(size_t)2*QS + ((size_t)(bb*NHEAD + h)*HD + d)*T_SEQ + t] = pk;
      }
    } else {
      #pragma unroll
      for (int mt = 0; mt < 4; mt++)
        #pragma unroll
        for (int r = 0; r < 4; r++){
          const int rowg = m0 + wm*64 + mt*16 + l4*4 + r;
          const int bb = rowg >> 11, t = rowg & 2047;
          out[(size_t)which*QS + ((size_t)(bb*NHEAD + h)*T_SEQ + t)*HD + d]
              = f2b((acc[mt][nt][r] + bias_v) * sc);
        }
    }
  }
}

// ---------------- GEMM (proj): same dbuf + swizzle, fp32 [M,N] out ----------
__global__ __launch_bounds__(256) void gemm_proj(
    const u16* __restrict__ A, const u16* __restrict__ Bt,
    const float* __restrict__ bias, float* __restrict__ out, int Ktot)
{
  __shared__ __align__(16) u16 As[2][128*64];
  __shared__ __align__(16) u16 Bs[2][128*64];
  const int tid = threadIdx.x;
  const int lane = tid & 63, wave = tid >> 6;
  const int l15 = lane & 15, l4 = lane >> 4;
  const int wm = wave >> 1, wn = wave & 1;
  // 512 blocks, 64 per XCD
  const int id = blockIdx.x;
  const int swz = (id & 7) * 64 + (id >> 3);
  const int m0 = (swz / 8) * 128, n0 = (swz % 8) * 128;
  const int NT = Ktot >> 6;

  f32x4 acc[4][4] = {};

  QSTAGE(0, 0);
  for (int c = 0; c < NT; c++){
    const int cur = c & 1;
    if (c + 1 < NT){
      QSTAGE(cur ^ 1, (c + 1) * 64);
      WAITV(8);
    } else {
      WAITV(0);
    }
    BARRIER();

    #pragma unroll
    for (int ks = 0; ks < 2; ks++){
      bf16x8 af[4], bfr[4];
      #pragma unroll
      for (int mt = 0; mt < 4; mt++){
        const int rf = wm*64 + mt*16 + l15;
        const int slot = rf*8 + ((ks*4 + l4) ^ (rf & 7));
        af[mt] = *(const bf16x8*)&As[cur][slot*8];
      }
      #pragma unroll
      for (int nt = 0; nt < 4; nt++){
        const int rf = wn*64 + nt*16 + l15;
        const int slot = rf*8 + ((ks*4 + l4) ^ (rf & 7));
        bfr[nt] = *(const bf16x8*)&Bs[cur][slot*8];
      }
      #pragma unroll
      for (int mt = 0; mt < 4; mt++)
        #pragma unroll
        for (int nt = 0; nt < 4; nt++)
          acc[mt][nt] = __builtin_amdgcn_mfma_f32_16x16x32_bf16(
              af[mt], bfr[nt], acc[mt][nt], 0, 0, 0);
    }
    BARRIER();
  }

  #pragma unroll
  for (int nt = 0; nt < 4; nt++){
    const int n = n0 + wn*64 + nt*16 + l15;
    const float bias_v = bias[n];
    #pragma unroll
    for (int mt = 0; mt < 4; mt++)
      #pragma unroll
      for (int r = 0; r < 4; r++){
        const int rowg = m0 + wm*64 + mt*16 + l4*4 + r;
        out[(size_t)rowg*CEMB + n] = acc[mt][nt][r] + bias_v;
      }
  }
}

// ---------------- causal flash attention, S^T, no-max softmax ----------------
// K/V double-buffered with counted vmcnt (unchanged from round 4; grid is
// already XCD-optimal: same-bh blocks are 64 apart == same XCD mod 8).
__global__ __launch_bounds__(256, 3) void attn_kernel(
    const u16* __restrict__ qb, const u16* __restrict__ kb,
    const u16* __restrict__ vtb, u16* __restrict__ y)
{
  __shared__ __align__(16) u16 Ks[2*64*64];   // swizzled, double-buffered
  __shared__ __align__(16) u16 Vt[2*64*64];   // swizzled (V^T rows [d][t])
  __shared__ __align__(16) u16 Pw[8*16*72];   // per (wave,group) P[q][t]
  const int tid = threadIdx.x;
  const int lane = tid & 63, wave = tid >> 6;
  const int l15 = lane & 15, l4 = lane >> 4;
  const int qt = 15 - (blockIdx.x >> 6);      // longest-first
  const int bh = blockIdx.x & 63;
  const int q0 = qt * 128;
  const size_t base = (size_t)bh * (T_SEQ * HD);
  const u16* qp  = qb  + base;
  const u16* kp  = kb  + base;
  const u16* vtp = vtb + base;                // [hd][T]

  const int qmin0 = q0 + wave*32;
  const int qmin1 = qmin0 + 16;

  // Q as B-operand frags for both groups
  bf16x8 qf[2][2];
  #pragma unroll
  for (int g = 0; g < 2; g++){
    const int m = qmin0 + g*16 + l15;
    qf[g][0] = *(const bf16x8*)&qp[m*HD +      l4*8];
    qf[g][1] = *(const bf16x8*)&qp[m*HD + 32 + l4*8];
  }
  f32x4 o[2][4] = {};
  float l_run[2] = {0.f, 0.f};

  // staging addresses (constant per thread): 2 chunks each for K and V
  const int s0i = (wave*2 + 0) * 64 + lane;
  const int s1i = (wave*2 + 1) * 64 + lane;
  const int row0 = s0i >> 3, c0 = (s0i & 7) ^ (row0 & 7);
  const int row1 = s1i >> 3, c1 = (s1i & 7) ^ (row1 & 7);
  const int koff0 = row0*HD + c0*8, koff1 = row1*HD + c1*8;
  const int voff0 = row0*T_SEQ + c0*8, voff1 = row1*T_SEQ + c1*8;
  const int ldso0 = (wave*2 + 0) * 64 * 8, ldso1 = (wave*2 + 1) * 64 * 8;

  const int nkt = 2*qt + 2;

  // prologue: stage tile 0 into buffer 0
  glds16(&kp [koff0], &Ks[ldso0]);
  glds16(&kp [koff1], &Ks[ldso1]);
  glds16(&vtp[voff0], &Vt[ldso0]);
  glds16(&vtp[voff1], &Vt[ldso1]);

  for (int kt = 0; kt < nkt; kt++){
    const int cb = (kt & 1) * 4096;           // current LDS buffer (u16 elems)
    if (kt + 1 < nkt){
      const int nb = ((kt + 1) & 1) * 4096;   // next buffer
      glds16(&kp [(kt+1)*4096 + koff0], &Ks[nb + ldso0]);
      glds16(&kp [(kt+1)*4096 + koff1], &Ks[nb + ldso1]);
      glds16(&vtp[(kt+1)*64   + voff0], &Vt[nb + ldso0]);
      glds16(&vtp[(kt+1)*64   + voff1], &Vt[nb + ldso1]);
      WAITV(4);                               // own tile-kt loads landed
    } else {
      WAITV(0);
    }
    BARRIER();                                // => every wave's kt data landed

    const int t0 = kt*64;
    if (t0 <= qmin1 + 15){                    // wave-uniform
      const bool act0 = (t0 <= qmin0 + 15);

      // S^T = K·Q^T for both groups, sharing each K fragment read
      f32x4 s0[4], s1[4];
      #pragma unroll
      for (int nb2 = 0; nb2 < 4; nb2++){
        f32x4 a0 = {}, a1 = {};
        #pragma unroll
        for (int ks = 0; ks < 2; ks++){
          const int rf = nb2*16 + l15;
          const int slot = rf*8 + ((ks*4 + l4) ^ (rf & 7));
          bf16x8 kf = *(const bf16x8*)&Ks[cb + slot*8];
          a1 = __builtin_amdgcn_mfma_f32_16x16x32_bf16(kf, qf[1][ks], a1, 0, 0, 0);
          if (act0)
            a0 = __builtin_amdgcn_mfma_f32_16x16x32_bf16(kf, qf[0][ks], a0, 0, 0, 0);
        }
        s1[nb2] = a1; s0[nb2] = a0;
      }

      // softmax (exp2 domain, no max tracking) + P write, per group
      #pragma unroll
      for (int g = 0; g < 2; g++){
        if (g == 0 && !act0) continue;
        f32x4* sf = (g == 0) ? s0 : s1;
        const int qmin = (g == 0) ? qmin0 : qmin1;
        const int qg = qmin + l15;
        float lsum = 0.f;
        if (t0 + 63 > qmin){                  // diagonal-region tile: mask
          #pragma unroll
          for (int nb2 = 0; nb2 < 4; nb2++){
            u16x4 pk;
            #pragma unroll
            for (int r = 0; r < 4; r++){
              const int t = t0 + nb2*16 + l4*4 + r;
              float p = __builtin_amdgcn_exp2f(sf[nb2][r]);
              p = (t <= qg) ? p : 0.0f;
              lsum += p;
              pk[r] = f2b(p);
            }
            *(u16x4*)&Pw[(wave*2 + g)*1152 + l15*72 + nb2*16 + l4*4] = pk;
          }
        } else {
          #pragma unroll
          for (int nb2 = 0; nb2 < 4; nb2++){
            u16x4 pk;
            #pragma unroll
            for (int r = 0; r < 4; r++){
              const float p = __builtin_amdgcn_exp2f(sf[nb2][r]);
              lsum += p;
              pk[r] = f2b(p);
            }
            *(u16x4*)&Pw[(wave*2 + g)*1152 + l15*72 + nb2*16 + l4*4] = pk;
          }
        }
        l_run[g] += lsum;
      }

      // O^T += V^T·P^T, sharing each V fragment read between groups
      #pragma unroll
      for (int ks = 0; ks < 2; ks++){
        bf16x8 pf1 = *(const bf16x8*)&Pw[(wave*2 + 1)*1152 + l15*72 + ks*32 + l4*8];
        bf16x8 pf0;
        if (act0) pf0 = *(const bf16x8*)&Pw[(wave*2 + 0)*1152 + l15*72 + ks*32 + l4*8];
        #pragma unroll
        for (int nh = 0; nh < 4; nh++){
          const int rf = nh*16 + l15;
          const int slot = rf*8 + ((ks*4 + l4) ^ (rf & 7));
          bf16x8 vf = *(const bf16x8*)&Vt[cb + slot*8];
          o[1][nh] = __builtin_amdgcn_mfma_f32_16x16x32_bf16(vf, pf1, o[1][nh], 0, 0, 0);
          if (act0)
            o[0][nh] = __builtin_amdgcn_mfma_f32_16x16x32_bf16(vf, pf0, o[0][nh], 0, 0, 0);
        }
      }
    }
    BARRIER();                                // reads done before buffer reuse
  }

  // epilogue per group: O^T[d][q]; lane q = l15; d = nh*16 + l4*4 + r
  const int b = bh >> 4, h = bh & 15;
  #pragma unroll
  for (int g = 0; g < 2; g++){
    float lr = l_run[g];
    lr += __shfl_xor(lr, 16);
    lr += __shfl_xor(lr, 32);
    const float inv_l = 1.0f / lr;
    const int t = qmin0 + g*16 + l15;
    #pragma unroll
    for (int nh = 0; nh < 4; nh++){
      u16x4 pk;
      #pragma unroll
      for (int r = 0; r < 4; r++) pk[r] = f2b(o[g][nh][r] * inv_l);
      *(u16x4*)&y[((size_t)(b*T_SEQ + t))*CEMB + h*HD + nh*16 + l4*4] = pk;
    }
  }
}

extern "C" void kernel_launch(void* const* d_in, const int* in_sizes, int n_in,
                              void* d_out, int out_size, void* d_ws, size_t ws_size,
                              hipStream_t stream) {
  const float* x      = (const float*)d_in[0];
  const float* W_attn = (const float*)d_in[1];
  const float* b_attn = (const float*)d_in[2];
  const float* W_proj = (const float*)d_in[3];
  const float* b_proj = (const float*)d_in[4];
  float* out = (float*)d_out;
  u16* ws  = (u16*)d_ws;

  u16* Wt_attn = ws;                 // 3,145,728
  u16* Wt_proj = ws + 3145728;       // 1,048,576
  u16* xb      = ws + 4194304;       // 8,388,608 (x as bf16; reused as y)
  u16* qkv     = ws + 12582912;      // 3 * QS
  u16* y       = xb;                 // xb dead after QKV GEMM

  prep_kernel<<<5120, 256, 0, stream>>>(x, xb, W_attn, Wt_attn, W_proj, Wt_proj);
  gemm_qkv128<<<1536, 256, 0, stream>>>(xb, Wt_attn, b_attn, qkv, 1024);
  attn_kernel<<<1024, 256, 0, stream>>>(qkv, qkv + QS, qkv + 2*QS, y);
  gemm_proj<<<512, 256, 0, stream>>>(y, Wt_proj, b_proj, out, 1024);
}